// Round 1
// baseline (1965.751 us; speedup 1.0000x reference)
//
#include <hip/hip_runtime.h>
#include <math.h>

#define BB 8
#define NN 2048
#define KNN 20
#define BN_INV 0.9999950000374997f

// ---------------------------------------------------------------- unscramble
// x[b][n][c] = points_flat[b*6144 + c*2048 + n]; also sq = sum_c x^2
__global__ __launch_bounds__(256)
void k_unscramble(const float* __restrict__ pts, float* __restrict__ x0,
                  float* __restrict__ sq) {
  int t = blockIdx.x * 256 + threadIdx.x;
  if (t >= BB * NN) return;
  int b = t >> 11, n = t & (NN - 1);
  const float* p = pts + (size_t)b * 3 * NN;
  float a0 = p[n], a1 = p[NN + n], a2 = p[2 * NN + n];
  float* o = x0 + (size_t)t * 3;
  o[0] = a0; o[1] = a1; o[2] = a2;
  sq[t] = a0 * a0 + a1 * a1 + a2 * a2;
}

// ---------------------------------------------------------------- pd gemm
// score[i][j] = 2*dot(x_i,x_j) - sq[j]   (ranking-equivalent to reference pd)
// 64x64 tile, 256 threads, 4x4 per thread, K chunked by 32.
template <int C>
__global__ __launch_bounds__(256)
void k_pd(const float* __restrict__ Xin, int RS, const float* __restrict__ sq,
          float* __restrict__ pd, int b0) {
  constexpr int CH = (C < 32) ? C : 32;
  constexpr int CHP = (CH == 3) ? 3 : 36;
  __shared__ __align__(16) float Xi[64 * CHP];
  __shared__ __align__(16) float Xj[64 * CHP];
  int b = b0 + blockIdx.z;
  int i0 = blockIdx.x * 64, j0 = blockIdx.y * 64;
  const float* Xb = Xin + (size_t)b * NN * RS;
  int ti = threadIdx.x & 15, tj = threadIdx.x >> 4;
  float acc[4][4] = {};
  for (int c0 = 0; c0 < C; c0 += CH) {
    for (int t = threadIdx.x; t < 64 * CH; t += 256) {
      int r = t / CH, c = t % CH;
      Xi[r * CHP + c] = Xb[(size_t)(i0 + r) * RS + c0 + c];
      Xj[r * CHP + c] = Xb[(size_t)(j0 + r) * RS + c0 + c];
    }
    __syncthreads();
    if constexpr (CH % 4 == 0) {
      #pragma unroll
      for (int c = 0; c < CH; c += 4) {
        float4 ap[4], wq[4];
        #pragma unroll
        for (int p = 0; p < 4; p++) ap[p] = *(const float4*)&Xi[(ti * 4 + p) * CHP + c];
        #pragma unroll
        for (int q = 0; q < 4; q++) wq[q] = *(const float4*)&Xj[(tj * 4 + q) * CHP + c];
        #pragma unroll
        for (int p = 0; p < 4; p++)
          #pragma unroll
          for (int q = 0; q < 4; q++)
            acc[p][q] += ap[p].x * wq[q].x + ap[p].y * wq[q].y +
                         ap[p].z * wq[q].z + ap[p].w * wq[q].w;
      }
    } else {
      #pragma unroll
      for (int c = 0; c < CH; ++c) {
        float a[4], w[4];
        #pragma unroll
        for (int p = 0; p < 4; p++) a[p] = Xi[(ti * 4 + p) * CHP + c];
        #pragma unroll
        for (int q = 0; q < 4; q++) w[q] = Xj[(tj * 4 + q) * CHP + c];
        #pragma unroll
        for (int p = 0; p < 4; p++)
          #pragma unroll
          for (int q = 0; q < 4; q++) acc[p][q] += a[p] * w[q];
      }
    }
    __syncthreads();
  }
  const float* sqb = sq + (size_t)b * NN;
  float* pdb = pd + (size_t)blockIdx.z * NN * NN;
  #pragma unroll
  for (int p = 0; p < 4; p++) {
    int i = i0 + ti * 4 + p;
    int j = j0 + tj * 4;
    float4 o;
    o.x = 2.f * acc[p][0] - sqb[j + 0];
    o.y = 2.f * acc[p][1] - sqb[j + 1];
    o.z = 2.f * acc[p][2] - sqb[j + 2];
    o.w = 2.f * acc[p][3] - sqb[j + 3];
    *(float4*)&pdb[(size_t)i * NN + j] = o;
  }
}

// ---------------------------------------------------------------- knn select
// one wave per row; row cached in 32 regs/lane; 20x (local argmax via bitmask
// + wave shuffle argmax, lowest index wins ties)
__global__ __launch_bounds__(256)
void k_select(const float* __restrict__ pd, int* __restrict__ idx, int b0,
              int rows) {
  int wave = threadIdx.x >> 6;
  int lane = threadIdx.x & 63;
  int r = blockIdx.x * 4 + wave;  // slab-local row
  if (r >= rows) return;
  const float* row = pd + (size_t)r * NN;
  float rv[32];
  #pragma unroll
  for (int m = 0; m < 32; m++) rv[m] = row[m * 64 + lane];
  unsigned removed = 0u;
  int* out = idx + ((size_t)b0 * NN + r) * KNN;
  for (int k = 0; k < KNN; k++) {
    float lv = -INFINITY;
    int lm = 0;
    #pragma unroll
    for (int m = 0; m < 32; m++) {
      float vv = ((removed >> m) & 1u) ? -INFINITY : rv[m];
      if (vv > lv) { lv = vv; lm = m; }
    }
    float bv = lv;
    int bj = lm * 64 + lane;
    #pragma unroll
    for (int off = 32; off; off >>= 1) {
      float ov = __shfl_xor(bv, off, 64);
      int oj = __shfl_xor(bj, off, 64);
      if (ov > bv || (ov == bv && oj < bj)) { bv = ov; bj = oj; }
    }
    if (lane == 0) out[k] = bj;
    if (lane == (bj & 63)) removed |= (1u << (bj >> 6));
  }
}

// ---------------------------------------------------------------- y/v gemm
// y[n][o] = s_o * (Wa . x_n);  v[n][o] = s_o * ((Wb-Wa) . x_n) + b_o
template <int C, int O>
__global__ __launch_bounds__(256)
void k_yv(const float* __restrict__ Xin, int RS, const float* __restrict__ W,
          const float* __restrict__ g, const float* __restrict__ bbn,
          float* __restrict__ y, float* __restrict__ v) {
  constexpr int CH = (C < 32) ? C : 32;
  constexpr int CHP = (CH == 3) ? 3 : 36;
  __shared__ __align__(16) float Xs[64 * CHP];
  __shared__ __align__(16) float Wa[64 * CHP];
  __shared__ __align__(16) float Wd[64 * CHP];
  int r0 = blockIdx.x * 64, o0 = blockIdx.y * 64;
  int ti = threadIdx.x & 15, tj = threadIdx.x >> 4;
  float ay[4][4] = {}, av[4][4] = {};
  for (int c0 = 0; c0 < C; c0 += CH) {
    for (int t = threadIdx.x; t < 64 * CH; t += 256) {
      int r = t / CH, c = t % CH;
      Xs[r * CHP + c] = Xin[(size_t)(r0 + r) * RS + c0 + c];
      const float* wr = W + (size_t)(o0 + r) * (2 * C) + c0 + c;
      float wa_ = wr[0];
      Wa[r * CHP + c] = wa_;
      Wd[r * CHP + c] = wr[C] - wa_;
    }
    __syncthreads();
    if constexpr (CH % 4 == 0) {
      #pragma unroll
      for (int c = 0; c < CH; c += 4) {
        float4 ap[4], qa[4], qd[4];
        #pragma unroll
        for (int p = 0; p < 4; p++) ap[p] = *(const float4*)&Xs[(ti * 4 + p) * CHP + c];
        #pragma unroll
        for (int q = 0; q < 4; q++) {
          qa[q] = *(const float4*)&Wa[(tj * 4 + q) * CHP + c];
          qd[q] = *(const float4*)&Wd[(tj * 4 + q) * CHP + c];
        }
        #pragma unroll
        for (int p = 0; p < 4; p++)
          #pragma unroll
          for (int q = 0; q < 4; q++) {
            ay[p][q] += ap[p].x * qa[q].x + ap[p].y * qa[q].y +
                        ap[p].z * qa[q].z + ap[p].w * qa[q].w;
            av[p][q] += ap[p].x * qd[q].x + ap[p].y * qd[q].y +
                        ap[p].z * qd[q].z + ap[p].w * qd[q].w;
          }
      }
    } else {
      #pragma unroll
      for (int c = 0; c < CH; ++c) {
        float a[4];
        #pragma unroll
        for (int p = 0; p < 4; p++) a[p] = Xs[(ti * 4 + p) * CHP + c];
        #pragma unroll
        for (int q = 0; q < 4; q++) {
          float wa_ = Wa[(tj * 4 + q) * CHP + c];
          float wd_ = Wd[(tj * 4 + q) * CHP + c];
          #pragma unroll
          for (int p = 0; p < 4; p++) {
            ay[p][q] += a[p] * wa_;
            av[p][q] += a[p] * wd_;
          }
        }
      }
    }
    __syncthreads();
  }
  #pragma unroll
  for (int p = 0; p < 4; p++) {
    int row = r0 + ti * 4 + p;
    float oy[4], ov[4];
    #pragma unroll
    for (int q = 0; q < 4; q++) {
      int o = o0 + tj * 4 + q;
      float s = BN_INV * g[o];
      oy[q] = s * ay[p][q];
      ov[q] = s * av[p][q] + bbn[o];
    }
    *(float4*)&y[(size_t)row * O + o0 + tj * 4] = *(float4*)oy;
    *(float4*)&v[(size_t)row * O + o0 + tj * 4] = *(float4*)ov;
  }
}

// ---------------------------------------------------------------- aggregate
// out[n][o] = lrelu(max_k (y[idx[n][k]][o] + v[n][o])) -> cat; sq for next layer
template <int O, bool DO_SQ>
__global__ __launch_bounds__(256)
void k_agg(const float* __restrict__ y, const float* __restrict__ v,
           const int* __restrict__ idx, float* __restrict__ cat_out, int coloff,
           float* __restrict__ sqo) {
  constexpr int RPB = 256 / O;
  int rl = threadIdx.x / O;
  int o = threadIdx.x % O;
  int row = blockIdx.x * RPB + rl;  // b*N+n
  int b = row >> 11;
  const int* ix = idx + (size_t)row * KNN;
  float vv = v[(size_t)row * O + o];
  const float* yb = y + (size_t)b * NN * O;
  float m = -INFINITY;
  #pragma unroll
  for (int k = 0; k < KNN; k++) {
    int j = ix[k];
    m = fmaxf(m, yb[(size_t)j * O + o] + vv);
  }
  float out = m >= 0.f ? m : 0.2f * m;
  cat_out[(size_t)row * 512 + coloff + o] = out;
  if constexpr (DO_SQ) {
    constexpr int WPR = O / 64;
    float p2 = out * out;
    #pragma unroll
    for (int off = 32; off; off >>= 1) p2 += __shfl_xor(p2, off, 64);
    __shared__ float part[4];
    int wv = threadIdx.x >> 6;
    if ((threadIdx.x & 63) == 0) part[wv] = p2;
    __syncthreads();
    if ((threadIdx.x % O) == 0) {
      int w0 = threadIdx.x >> 6;
      float s = 0.f;
      #pragma unroll
      for (int w = 0; w < WPR; ++w) s += part[w0 + w];
      sqo[row] = s;
    }
  }
}

// ---------------------------------------------------------------- h5 gemm
// [16384,512] x [512,1024]^T, epilogue lrelu(bn)
__global__ __launch_bounds__(256)
void k_h5(const float* __restrict__ A, const float* __restrict__ W5,
          const float* __restrict__ g, const float* __restrict__ bbn,
          float* __restrict__ out) {
  __shared__ __align__(16) float As[64 * 36];
  __shared__ __align__(16) float Bs[64 * 36];
  int r0 = blockIdx.x * 64, o0 = blockIdx.y * 64;
  int ti = threadIdx.x & 15, tj = threadIdx.x >> 4;
  float acc[4][4] = {};
  for (int k0 = 0; k0 < 512; k0 += 32) {
    for (int t = threadIdx.x; t < 64 * 32; t += 256) {
      int r = t >> 5, c = t & 31;
      As[r * 36 + c] = A[(size_t)(r0 + r) * 512 + k0 + c];
      Bs[r * 36 + c] = W5[(size_t)(o0 + r) * 512 + k0 + c];
    }
    __syncthreads();
    #pragma unroll
    for (int c = 0; c < 32; c += 4) {
      float4 ap[4], wq[4];
      #pragma unroll
      for (int p = 0; p < 4; p++) ap[p] = *(const float4*)&As[(ti * 4 + p) * 36 + c];
      #pragma unroll
      for (int q = 0; q < 4; q++) wq[q] = *(const float4*)&Bs[(tj * 4 + q) * 36 + c];
      #pragma unroll
      for (int p = 0; p < 4; p++)
        #pragma unroll
        for (int q = 0; q < 4; q++)
          acc[p][q] += ap[p].x * wq[q].x + ap[p].y * wq[q].y +
                       ap[p].z * wq[q].z + ap[p].w * wq[q].w;
    }
    __syncthreads();
  }
  #pragma unroll
  for (int p = 0; p < 4; p++) {
    int row = r0 + ti * 4 + p;
    float ov[4];
    #pragma unroll
    for (int q = 0; q < 4; q++) {
      int o = o0 + tj * 4 + q;
      float z = BN_INV * g[o] * acc[p][q] + bbn[o];
      ov[q] = z >= 0.f ? z : 0.2f * z;
    }
    *(float4*)&out[(size_t)row * 1024 + o0 + tj * 4] = *(float4*)ov;
  }
}

// ---------------------------------------------------------------- reductions
__global__ __launch_bounds__(256)
void k_red1(const float* __restrict__ h5, float* __restrict__ pm,
            float* __restrict__ ps) {
  int oc = blockIdx.x, ns = blockIdx.y, b = blockIdx.z;
  int o = oc * 256 + threadIdx.x;
  const float* hp = h5 + ((size_t)b * NN + ns * 256) * 1024 + o;
  float m = -INFINITY, s = 0.f;
  for (int t = 0; t < 256; ++t) {
    float x = hp[(size_t)t * 1024];
    m = fmaxf(m, x);
    s += x;
  }
  pm[(size_t)(b * 8 + ns) * 1024 + o] = m;
  ps[(size_t)(b * 8 + ns) * 1024 + o] = s;
}

__global__ __launch_bounds__(256)
void k_red2(const float* __restrict__ pm, const float* __restrict__ ps,
            float* __restrict__ feat) {
  int gg = blockIdx.x * 256 + threadIdx.x;
  if (gg >= BB * 1024) return;
  int b = gg >> 10, o = gg & 1023;
  float m = -INFINITY, s = 0.f;
  for (int ns = 0; ns < 8; ++ns) {
    m = fmaxf(m, pm[(size_t)(b * 8 + ns) * 1024 + o]);
    s += ps[(size_t)(b * 8 + ns) * 1024 + o];
  }
  feat[(size_t)b * 2048 + o] = m;
  feat[(size_t)b * 2048 + 1024 + o] = s * (1.f / 2048.f);
}

// ---------------------------------------------------------------- FC layers
// mode 0: lrelu(bn(acc))   mode 1: lrelu(bn(acc+eb))   mode 2: acc+eb
__global__ __launch_bounds__(256)
void k_fc(const float* __restrict__ in, const float* __restrict__ W,
          const float* __restrict__ g, const float* __restrict__ bbn,
          const float* __restrict__ eb, float* __restrict__ out, int IN, int O,
          int mode) {
  int gid = (blockIdx.x * 256 + threadIdx.x) >> 6;
  int lane = threadIdx.x & 63;
  int b = gid / O, o = gid % O;
  if (b >= BB) return;
  const float* ip = in + (size_t)b * IN;
  const float* wp = W + (size_t)o * IN;
  float acc = 0.f;
  for (int i = lane; i < IN; i += 64) acc += ip[i] * wp[i];
  #pragma unroll
  for (int off = 32; off; off >>= 1) acc += __shfl_xor(acc, off, 64);
  if (lane == 0) {
    float z;
    if (mode == 0) {
      z = BN_INV * g[o] * acc + bbn[o];
      z = z >= 0.f ? z : 0.2f * z;
    } else if (mode == 1) {
      z = BN_INV * g[o] * (acc + eb[o]) + bbn[o];
      z = z >= 0.f ? z : 0.2f * z;
    } else {
      z = acc + eb[o];
    }
    out[(size_t)b * O + o] = z;
  }
}

// ---------------------------------------------------------------- host
extern "C" void kernel_launch(void* const* d_in, const int* in_sizes, int n_in,
                              void* d_out, int out_size, void* d_ws,
                              size_t ws_size, hipStream_t stream) {
  (void)in_sizes; (void)n_in; (void)out_size;
  const float* pts = (const float*)d_in[0];
  const float* W1 = (const float*)d_in[1];
  const float* g1 = (const float*)d_in[2];
  const float* b1 = (const float*)d_in[3];
  const float* W2 = (const float*)d_in[4];
  const float* g2 = (const float*)d_in[5];
  const float* b2 = (const float*)d_in[6];
  const float* W3 = (const float*)d_in[7];
  const float* g3 = (const float*)d_in[8];
  const float* b3 = (const float*)d_in[9];
  const float* W4 = (const float*)d_in[10];
  const float* g4 = (const float*)d_in[11];
  const float* b4 = (const float*)d_in[12];
  const float* W5 = (const float*)d_in[13];
  const float* g5 = (const float*)d_in[14];
  const float* b5 = (const float*)d_in[15];
  const float* Wl1 = (const float*)d_in[16];
  const float* g6 = (const float*)d_in[17];
  const float* b6 = (const float*)d_in[18];
  const float* Wl2 = (const float*)d_in[19];
  const float* bl2 = (const float*)d_in[20];
  const float* g7 = (const float*)d_in[21];
  const float* b7 = (const float*)d_in[22];
  const float* Wl3 = (const float*)d_in[23];
  const float* bl3 = (const float*)d_in[24];

  char* ws = (char*)d_ws;
  float* x0 = (float*)(ws + 0);                  // 196608
  float* cat = (float*)(ws + 196608);            // 33554432
  float* sq = (float*)(ws + 33751040);           // 65536
  int* idx = (int*)(ws + 33816576);              // 1310720
  float* y = (float*)(ws + 35127296);            // 16777216
  float* v = (float*)(ws + 51904512);            // 16777216
  float* pm = (float*)(ws + 68681728);           // 262144
  float* ps = (float*)(ws + 68943872);           // 262144
  float* feat = (float*)(ws + 69206016);         // 65536
  float* fc1o = (float*)(ws + 69271552);         // 16384
  float* fc2o = (float*)(ws + 69287936);         // 8192
  float* big = (float*)(ws + 69296128);          // pd slab / h5 (shared)

  size_t avail = ws_size > (size_t)69296128 ? ws_size - (size_t)69296128 : 0;
  int slabB = (int)(avail / ((size_t)NN * NN * 4));
  if (slabB > BB) slabB = BB;
  if (slabB < 1) slabB = 1;

  k_unscramble<<<dim3(64), 256, 0, stream>>>(pts, x0, sq);

  // ---- layer 1: C=3 O=64, in=x0(RS 3), out cols [0,64)
  for (int b0 = 0; b0 < BB; b0 += slabB) {
    int sb = BB - b0 < slabB ? BB - b0 : slabB;
    k_pd<3><<<dim3(32, 32, sb), 256, 0, stream>>>(x0, 3, sq, big, b0);
    k_select<<<dim3(sb * NN / 4), 256, 0, stream>>>(big, idx, b0, sb * NN);
  }
  k_yv<3, 64><<<dim3(256, 1), 256, 0, stream>>>(x0, 3, W1, g1, b1, y, v);
  k_agg<64, true><<<dim3(BB * NN / 4), 256, 0, stream>>>(y, v, idx, cat, 0, sq);

  // ---- layer 2: C=64 O=64, in=cat[:,0:64), out cols [64,128)
  for (int b0 = 0; b0 < BB; b0 += slabB) {
    int sb = BB - b0 < slabB ? BB - b0 : slabB;
    k_pd<64><<<dim3(32, 32, sb), 256, 0, stream>>>(cat, 512, sq, big, b0);
    k_select<<<dim3(sb * NN / 4), 256, 0, stream>>>(big, idx, b0, sb * NN);
  }
  k_yv<64, 64><<<dim3(256, 1), 256, 0, stream>>>(cat, 512, W2, g2, b2, y, v);
  k_agg<64, true><<<dim3(BB * NN / 4), 256, 0, stream>>>(y, v, idx, cat, 64, sq);

  // ---- layer 3: C=64 O=128, in=cat[:,64:128), out cols [128,256)
  for (int b0 = 0; b0 < BB; b0 += slabB) {
    int sb = BB - b0 < slabB ? BB - b0 : slabB;
    k_pd<64><<<dim3(32, 32, sb), 256, 0, stream>>>(cat + 64, 512, sq, big, b0);
    k_select<<<dim3(sb * NN / 4), 256, 0, stream>>>(big, idx, b0, sb * NN);
  }
  k_yv<64, 128><<<dim3(256, 2), 256, 0, stream>>>(cat + 64, 512, W3, g3, b3, y, v);
  k_agg<128, true><<<dim3(BB * NN / 2), 256, 0, stream>>>(y, v, idx, cat, 128, sq);

  // ---- layer 4: C=128 O=256, in=cat[:,128:256), out cols [256,512)
  for (int b0 = 0; b0 < BB; b0 += slabB) {
    int sb = BB - b0 < slabB ? BB - b0 : slabB;
    k_pd<128><<<dim3(32, 32, sb), 256, 0, stream>>>(cat + 128, 512, sq, big, b0);
    k_select<<<dim3(sb * NN / 4), 256, 0, stream>>>(big, idx, b0, sb * NN);
  }
  k_yv<128, 256><<<dim3(256, 4), 256, 0, stream>>>(cat + 128, 512, W4, g4, b4, y, v);
  k_agg<256, false><<<dim3(BB * NN), 256, 0, stream>>>(y, v, idx, cat, 256, nullptr);

  // ---- h5 + feat
  float* h5b = big;
  k_h5<<<dim3(256, 16), 256, 0, stream>>>(cat, W5, g5, b5, h5b);
  k_red1<<<dim3(4, 8, 8), 256, 0, stream>>>(h5b, pm, ps);
  k_red2<<<dim3(32), 256, 0, stream>>>(pm, ps, feat);

  // ---- FC head
  k_fc<<<dim3(1024), 256, 0, stream>>>(feat, Wl1, g6, b6, nullptr, fc1o, 2048, 512, 0);
  k_fc<<<dim3(512), 256, 0, stream>>>(fc1o, Wl2, g7, b7, bl2, fc2o, 512, 256, 1);
  k_fc<<<dim3(80), 256, 0, stream>>>(fc2o, Wl3, nullptr, nullptr, bl3, (float*)d_out, 256, 40, 2);
}

// Round 2
// 1362.003 us; speedup vs baseline: 1.4433x; 1.4433x over previous
//
#include <hip/hip_runtime.h>
#include <math.h>

#define BB 8
#define NN 2048
#define KNN 20
#define BN_INV 0.9999950000374997f

// ---------------------------------------------------------------- unscramble
// x[b][n][c] = points_flat[b*6144 + c*2048 + n]; also sq = sum_c x^2
__global__ __launch_bounds__(256)
void k_unscramble(const float* __restrict__ pts, float* __restrict__ x0,
                  float* __restrict__ sq) {
  int t = blockIdx.x * 256 + threadIdx.x;
  if (t >= BB * NN) return;
  int b = t >> 11, n = t & (NN - 1);
  const float* p = pts + (size_t)b * 3 * NN;
  float a0 = p[n], a1 = p[NN + n], a2 = p[2 * NN + n];
  float* o = x0 + (size_t)t * 3;
  o[0] = a0; o[1] = a1; o[2] = a2;
  sq[t] = a0 * a0 + a1 * a1 + a2 * a2;
}

// ---------------------------------------------------------------- pd gemm
// score[i][j] = 2*dot(x_i,x_j) - sq[j]   (ranking-equivalent to reference pd)
// 64x64 tile, 256 threads, 4x4 per thread (A-rows STRIDED ti+16p to avoid
// LDS bank conflicts: lane stride 144B -> 8 bank-quads, 2-way = free)
template <int C>
__global__ __launch_bounds__(256)
void k_pd(const float* __restrict__ Xin, int RS, const float* __restrict__ sq,
          float* __restrict__ pd, int b0) {
  constexpr int CH = (C < 32) ? C : 32;
  constexpr int CHP = (CH == 3) ? 3 : 36;
  __shared__ __align__(16) float Xi[64 * CHP];
  __shared__ __align__(16) float Xj[64 * CHP];
  int b = b0 + blockIdx.z;
  int i0 = blockIdx.x * 64, j0 = blockIdx.y * 64;
  const float* Xb = Xin + (size_t)b * NN * RS;
  int ti = threadIdx.x & 15, tj = threadIdx.x >> 4;
  float acc[4][4] = {};
  for (int c0 = 0; c0 < C; c0 += CH) {
    if constexpr (CH == 32) {
      for (int t = threadIdx.x; t < 64 * 8; t += 256) {
        int r = t >> 3, c = (t & 7) * 4;
        *(float4*)&Xi[r * CHP + c] =
            *(const float4*)&Xb[(size_t)(i0 + r) * RS + c0 + c];
        *(float4*)&Xj[r * CHP + c] =
            *(const float4*)&Xb[(size_t)(j0 + r) * RS + c0 + c];
      }
    } else {
      for (int t = threadIdx.x; t < 64 * CH; t += 256) {
        int r = t / CH, c = t % CH;
        Xi[r * CHP + c] = Xb[(size_t)(i0 + r) * RS + c0 + c];
        Xj[r * CHP + c] = Xb[(size_t)(j0 + r) * RS + c0 + c];
      }
    }
    __syncthreads();
    if constexpr (CH % 4 == 0) {
      #pragma unroll
      for (int c = 0; c < CH; c += 4) {
        float4 ap[4], wq[4];
        #pragma unroll
        for (int p = 0; p < 4; p++)
          ap[p] = *(const float4*)&Xi[(ti + 16 * p) * CHP + c];
        #pragma unroll
        for (int q = 0; q < 4; q++)
          wq[q] = *(const float4*)&Xj[(tj * 4 + q) * CHP + c];
        #pragma unroll
        for (int p = 0; p < 4; p++)
          #pragma unroll
          for (int q = 0; q < 4; q++)
            acc[p][q] += ap[p].x * wq[q].x + ap[p].y * wq[q].y +
                         ap[p].z * wq[q].z + ap[p].w * wq[q].w;
      }
    } else {
      #pragma unroll
      for (int c = 0; c < CH; ++c) {
        float a[4], w[4];
        #pragma unroll
        for (int p = 0; p < 4; p++) a[p] = Xi[(ti + 16 * p) * CHP + c];
        #pragma unroll
        for (int q = 0; q < 4; q++) w[q] = Xj[(tj * 4 + q) * CHP + c];
        #pragma unroll
        for (int p = 0; p < 4; p++)
          #pragma unroll
          for (int q = 0; q < 4; q++) acc[p][q] += a[p] * w[q];
      }
    }
    __syncthreads();
  }
  const float* sqb = sq + (size_t)b * NN;
  float* pdb = pd + (size_t)blockIdx.z * NN * NN;
  #pragma unroll
  for (int p = 0; p < 4; p++) {
    int i = i0 + ti + 16 * p;
    int j = j0 + tj * 4;
    float4 o;
    o.x = 2.f * acc[p][0] - sqb[j + 0];
    o.y = 2.f * acc[p][1] - sqb[j + 1];
    o.z = 2.f * acc[p][2] - sqb[j + 2];
    o.w = 2.f * acc[p][3] - sqb[j + 3];
    *(float4*)&pdb[(size_t)i * NN + j] = o;
  }
}

// ---------------------------------------------------------------- knn select
// one wave per row; row cached in 32 regs/lane; 20x (local argmax via bitmask
// + wave shuffle argmax, lowest index wins ties)
__global__ __launch_bounds__(256)
void k_select(const float* __restrict__ pd, int* __restrict__ idx, int b0,
              int rows) {
  int wave = threadIdx.x >> 6;
  int lane = threadIdx.x & 63;
  int r = blockIdx.x * 4 + wave;  // slab-local row
  if (r >= rows) return;
  const float* row = pd + (size_t)r * NN;
  float rv[32];
  #pragma unroll
  for (int m = 0; m < 32; m++) rv[m] = row[m * 64 + lane];
  unsigned removed = 0u;
  int* out = idx + ((size_t)b0 * NN + r) * KNN;
  for (int k = 0; k < KNN; k++) {
    float lv = -INFINITY;
    int lm = 0;
    #pragma unroll
    for (int m = 0; m < 32; m++) {
      float vv = ((removed >> m) & 1u) ? -INFINITY : rv[m];
      if (vv > lv) { lv = vv; lm = m; }
    }
    float bv = lv;
    int bj = lm * 64 + lane;
    #pragma unroll
    for (int off = 32; off; off >>= 1) {
      float ov = __shfl_xor(bv, off, 64);
      int oj = __shfl_xor(bj, off, 64);
      if (ov > bv || (ov == bv && oj < bj)) { bv = ov; bj = oj; }
    }
    if (lane == 0) out[k] = bj;
    if (lane == (bj & 63)) removed |= (1u << (bj >> 6));
  }
}

// ---------------------------------------------------------------- y/v gemm
// y[n][o] = s_o * (Wa . x_n);  v[n][o] = s_o * ((Wb-Wa) . x_n) + b_o
template <int C, int O>
__global__ __launch_bounds__(256)
void k_yv(const float* __restrict__ Xin, int RS, const float* __restrict__ W,
          const float* __restrict__ g, const float* __restrict__ bbn,
          float* __restrict__ y, float* __restrict__ v) {
  constexpr int CH = (C < 32) ? C : 32;
  constexpr int CHP = (CH == 3) ? 3 : 36;
  __shared__ __align__(16) float Xs[64 * CHP];
  __shared__ __align__(16) float Wa[64 * CHP];
  __shared__ __align__(16) float Wd[64 * CHP];
  int r0 = blockIdx.x * 64, o0 = blockIdx.y * 64;
  int ti = threadIdx.x & 15, tj = threadIdx.x >> 4;
  float ay[4][4] = {}, av[4][4] = {};
  for (int c0 = 0; c0 < C; c0 += CH) {
    if constexpr (CH == 32) {
      for (int t = threadIdx.x; t < 64 * 8; t += 256) {
        int r = t >> 3, c = (t & 7) * 4;
        *(float4*)&Xs[r * CHP + c] =
            *(const float4*)&Xin[(size_t)(r0 + r) * RS + c0 + c];
        const float* wr = W + (size_t)(o0 + r) * (2 * C) + c0 + c;
        float4 wa4 = *(const float4*)wr;
        float4 wb4 = *(const float4*)(wr + C);
        *(float4*)&Wa[r * CHP + c] = wa4;
        float4 wd4;
        wd4.x = wb4.x - wa4.x; wd4.y = wb4.y - wa4.y;
        wd4.z = wb4.z - wa4.z; wd4.w = wb4.w - wa4.w;
        *(float4*)&Wd[r * CHP + c] = wd4;
      }
    } else {
      for (int t = threadIdx.x; t < 64 * CH; t += 256) {
        int r = t / CH, c = t % CH;
        Xs[r * CHP + c] = Xin[(size_t)(r0 + r) * RS + c0 + c];
        const float* wr = W + (size_t)(o0 + r) * (2 * C) + c0 + c;
        float wa_ = wr[0];
        Wa[r * CHP + c] = wa_;
        Wd[r * CHP + c] = wr[C] - wa_;
      }
    }
    __syncthreads();
    if constexpr (CH % 4 == 0) {
      #pragma unroll
      for (int c = 0; c < CH; c += 4) {
        float4 ap[4], qa[4], qd[4];
        #pragma unroll
        for (int p = 0; p < 4; p++)
          ap[p] = *(const float4*)&Xs[(ti + 16 * p) * CHP + c];
        #pragma unroll
        for (int q = 0; q < 4; q++) {
          qa[q] = *(const float4*)&Wa[(tj * 4 + q) * CHP + c];
          qd[q] = *(const float4*)&Wd[(tj * 4 + q) * CHP + c];
        }
        #pragma unroll
        for (int p = 0; p < 4; p++)
          #pragma unroll
          for (int q = 0; q < 4; q++) {
            ay[p][q] += ap[p].x * qa[q].x + ap[p].y * qa[q].y +
                        ap[p].z * qa[q].z + ap[p].w * qa[q].w;
            av[p][q] += ap[p].x * qd[q].x + ap[p].y * qd[q].y +
                        ap[p].z * qd[q].z + ap[p].w * qd[q].w;
          }
      }
    } else {
      #pragma unroll
      for (int c = 0; c < CH; ++c) {
        float a[4];
        #pragma unroll
        for (int p = 0; p < 4; p++) a[p] = Xs[(ti + 16 * p) * CHP + c];
        #pragma unroll
        for (int q = 0; q < 4; q++) {
          float wa_ = Wa[(tj * 4 + q) * CHP + c];
          float wd_ = Wd[(tj * 4 + q) * CHP + c];
          #pragma unroll
          for (int p = 0; p < 4; p++) {
            ay[p][q] += a[p] * wa_;
            av[p][q] += a[p] * wd_;
          }
        }
      }
    }
    __syncthreads();
  }
  #pragma unroll
  for (int p = 0; p < 4; p++) {
    int row = r0 + ti + 16 * p;
    float oy[4], ov[4];
    #pragma unroll
    for (int q = 0; q < 4; q++) {
      int o = o0 + tj * 4 + q;
      float s = BN_INV * g[o];
      oy[q] = s * ay[p][q];
      ov[q] = s * av[p][q] + bbn[o];
    }
    *(float4*)&y[(size_t)row * O + o0 + tj * 4] = *(float4*)oy;
    *(float4*)&v[(size_t)row * O + o0 + tj * 4] = *(float4*)ov;
  }
}

// ---------------------------------------------------------------- aggregate
// out[n][o] = lrelu(max_k (y[idx[n][k]][o] + v[n][o])) -> cat; sq for next layer
template <int O, bool DO_SQ>
__global__ __launch_bounds__(256)
void k_agg(const float* __restrict__ y, const float* __restrict__ v,
           const int* __restrict__ idx, float* __restrict__ cat_out, int coloff,
           float* __restrict__ sqo) {
  constexpr int RPB = 256 / O;
  int rl = threadIdx.x / O;
  int o = threadIdx.x % O;
  int row = blockIdx.x * RPB + rl;  // b*N+n
  int b = row >> 11;
  const int* ix = idx + (size_t)row * KNN;
  float vv = v[(size_t)row * O + o];
  const float* yb = y + (size_t)b * NN * O;
  float m = -INFINITY;
  #pragma unroll
  for (int k = 0; k < KNN; k++) {
    int j = ix[k];
    m = fmaxf(m, yb[(size_t)j * O + o] + vv);
  }
  float out = m >= 0.f ? m : 0.2f * m;
  cat_out[(size_t)row * 512 + coloff + o] = out;
  if constexpr (DO_SQ) {
    constexpr int WPR = O / 64;
    float p2 = out * out;
    #pragma unroll
    for (int off = 32; off; off >>= 1) p2 += __shfl_xor(p2, off, 64);
    __shared__ float part[4];
    int wv = threadIdx.x >> 6;
    if ((threadIdx.x & 63) == 0) part[wv] = p2;
    __syncthreads();
    if ((threadIdx.x % O) == 0) {
      int w0 = threadIdx.x >> 6;
      float s = 0.f;
      #pragma unroll
      for (int w = 0; w < WPR; ++w) s += part[w0 + w];
      sqo[row] = s;
    }
  }
}

// ---------------------------------------------------------------- h5 gemm
// [16384,512] x [512,1024]^T, epilogue lrelu(bn)
__global__ __launch_bounds__(256)
void k_h5(const float* __restrict__ A, const float* __restrict__ W5,
          const float* __restrict__ g, const float* __restrict__ bbn,
          float* __restrict__ out) {
  __shared__ __align__(16) float As[64 * 36];
  __shared__ __align__(16) float Bs[64 * 36];
  int r0 = blockIdx.x * 64, o0 = blockIdx.y * 64;
  int ti = threadIdx.x & 15, tj = threadIdx.x >> 4;
  float acc[4][4] = {};
  for (int k0 = 0; k0 < 512; k0 += 32) {
    for (int t = threadIdx.x; t < 64 * 8; t += 256) {
      int r = t >> 3, c = (t & 7) * 4;
      *(float4*)&As[r * 36 + c] =
          *(const float4*)&A[(size_t)(r0 + r) * 512 + k0 + c];
      *(float4*)&Bs[r * 36 + c] =
          *(const float4*)&W5[(size_t)(o0 + r) * 512 + k0 + c];
    }
    __syncthreads();
    #pragma unroll
    for (int c = 0; c < 32; c += 4) {
      float4 ap[4], wq[4];
      #pragma unroll
      for (int p = 0; p < 4; p++)
        ap[p] = *(const float4*)&As[(ti + 16 * p) * 36 + c];
      #pragma unroll
      for (int q = 0; q < 4; q++)
        wq[q] = *(const float4*)&Bs[(tj * 4 + q) * 36 + c];
      #pragma unroll
      for (int p = 0; p < 4; p++)
        #pragma unroll
        for (int q = 0; q < 4; q++)
          acc[p][q] += ap[p].x * wq[q].x + ap[p].y * wq[q].y +
                       ap[p].z * wq[q].z + ap[p].w * wq[q].w;
    }
    __syncthreads();
  }
  #pragma unroll
  for (int p = 0; p < 4; p++) {
    int row = r0 + ti + 16 * p;
    float ov[4];
    #pragma unroll
    for (int q = 0; q < 4; q++) {
      int o = o0 + tj * 4 + q;
      float z = BN_INV * g[o] * acc[p][q] + bbn[o];
      ov[q] = z >= 0.f ? z : 0.2f * z;
    }
    *(float4*)&out[(size_t)row * 1024 + o0 + tj * 4] = *(float4*)ov;
  }
}

// ---------------------------------------------------------------- reductions
__global__ __launch_bounds__(256)
void k_red1(const float* __restrict__ h5, float* __restrict__ pm,
            float* __restrict__ ps) {
  int oc = blockIdx.x, ns = blockIdx.y, b = blockIdx.z;
  int o = oc * 256 + threadIdx.x;
  const float* hp = h5 + ((size_t)b * NN + ns * 256) * 1024 + o;
  float m = -INFINITY, s = 0.f;
  for (int t = 0; t < 256; ++t) {
    float x = hp[(size_t)t * 1024];
    m = fmaxf(m, x);
    s += x;
  }
  pm[(size_t)(b * 8 + ns) * 1024 + o] = m;
  ps[(size_t)(b * 8 + ns) * 1024 + o] = s;
}

__global__ __launch_bounds__(256)
void k_red2(const float* __restrict__ pm, const float* __restrict__ ps,
            float* __restrict__ feat) {
  int gg = blockIdx.x * 256 + threadIdx.x;
  if (gg >= BB * 1024) return;
  int b = gg >> 10, o = gg & 1023;
  float m = -INFINITY, s = 0.f;
  for (int ns = 0; ns < 8; ++ns) {
    m = fmaxf(m, pm[(size_t)(b * 8 + ns) * 1024 + o]);
    s += ps[(size_t)(b * 8 + ns) * 1024 + o];
  }
  feat[(size_t)b * 2048 + o] = m;
  feat[(size_t)b * 2048 + 1024 + o] = s * (1.f / 2048.f);
}

// ---------------------------------------------------------------- FC layers
// mode 0: lrelu(bn(acc))   mode 1: lrelu(bn(acc+eb))   mode 2: acc+eb
__global__ __launch_bounds__(256)
void k_fc(const float* __restrict__ in, const float* __restrict__ W,
          const float* __restrict__ g, const float* __restrict__ bbn,
          const float* __restrict__ eb, float* __restrict__ out, int IN, int O,
          int mode) {
  int gid = (blockIdx.x * 256 + threadIdx.x) >> 6;
  int lane = threadIdx.x & 63;
  int b = gid / O, o = gid % O;
  if (b >= BB) return;
  const float* ip = in + (size_t)b * IN;
  const float* wp = W + (size_t)o * IN;
  float acc = 0.f;
  for (int i = lane; i < IN; i += 64) acc += ip[i] * wp[i];
  #pragma unroll
  for (int off = 32; off; off >>= 1) acc += __shfl_xor(acc, off, 64);
  if (lane == 0) {
    float z;
    if (mode == 0) {
      z = BN_INV * g[o] * acc + bbn[o];
      z = z >= 0.f ? z : 0.2f * z;
    } else if (mode == 1) {
      z = BN_INV * g[o] * (acc + eb[o]) + bbn[o];
      z = z >= 0.f ? z : 0.2f * z;
    } else {
      z = acc + eb[o];
    }
    out[(size_t)b * O + o] = z;
  }
}

// ---------------------------------------------------------------- host
extern "C" void kernel_launch(void* const* d_in, const int* in_sizes, int n_in,
                              void* d_out, int out_size, void* d_ws,
                              size_t ws_size, hipStream_t stream) {
  (void)in_sizes; (void)n_in; (void)out_size;
  const float* pts = (const float*)d_in[0];
  const float* W1 = (const float*)d_in[1];
  const float* g1 = (const float*)d_in[2];
  const float* b1 = (const float*)d_in[3];
  const float* W2 = (const float*)d_in[4];
  const float* g2 = (const float*)d_in[5];
  const float* b2 = (const float*)d_in[6];
  const float* W3 = (const float*)d_in[7];
  const float* g3 = (const float*)d_in[8];
  const float* b3 = (const float*)d_in[9];
  const float* W4 = (const float*)d_in[10];
  const float* g4 = (const float*)d_in[11];
  const float* b4 = (const float*)d_in[12];
  const float* W5 = (const float*)d_in[13];
  const float* g5 = (const float*)d_in[14];
  const float* b5 = (const float*)d_in[15];
  const float* Wl1 = (const float*)d_in[16];
  const float* g6 = (const float*)d_in[17];
  const float* b6 = (const float*)d_in[18];
  const float* Wl2 = (const float*)d_in[19];
  const float* bl2 = (const float*)d_in[20];
  const float* g7 = (const float*)d_in[21];
  const float* b7 = (const float*)d_in[22];
  const float* Wl3 = (const float*)d_in[23];
  const float* bl3 = (const float*)d_in[24];

  char* ws = (char*)d_ws;
  float* x0 = (float*)(ws + 0);                  // 196608
  float* cat = (float*)(ws + 196608);            // 33554432
  float* sq = (float*)(ws + 33751040);           // 65536
  int* idx = (int*)(ws + 33816576);              // 1310720
  float* y = (float*)(ws + 35127296);            // 16777216
  float* v = (float*)(ws + 51904512);            // 16777216
  float* pm = (float*)(ws + 68681728);           // 262144
  float* ps = (float*)(ws + 68943872);           // 262144
  float* feat = (float*)(ws + 69206016);         // 65536
  float* fc1o = (float*)(ws + 69271552);         // 16384
  float* fc2o = (float*)(ws + 69287936);         // 8192
  float* big = (float*)(ws + 69296128);          // pd slab / h5 (shared)

  size_t avail = ws_size > (size_t)69296128 ? ws_size - (size_t)69296128 : 0;
  int slabB = (int)(avail / ((size_t)NN * NN * 4));
  if (slabB > BB) slabB = BB;
  if (slabB < 1) slabB = 1;

  k_unscramble<<<dim3(64), 256, 0, stream>>>(pts, x0, sq);

  // ---- layer 1: C=3 O=64, in=x0(RS 3), out cols [0,64)
  for (int b0 = 0; b0 < BB; b0 += slabB) {
    int sb = BB - b0 < slabB ? BB - b0 : slabB;
    k_pd<3><<<dim3(32, 32, sb), 256, 0, stream>>>(x0, 3, sq, big, b0);
    k_select<<<dim3(sb * NN / 4), 256, 0, stream>>>(big, idx, b0, sb * NN);
  }
  k_yv<3, 64><<<dim3(256, 1), 256, 0, stream>>>(x0, 3, W1, g1, b1, y, v);
  k_agg<64, true><<<dim3(BB * NN / 4), 256, 0, stream>>>(y, v, idx, cat, 0, sq);

  // ---- layer 2: C=64 O=64, in=cat[:,0:64), out cols [64,128)
  for (int b0 = 0; b0 < BB; b0 += slabB) {
    int sb = BB - b0 < slabB ? BB - b0 : slabB;
    k_pd<64><<<dim3(32, 32, sb), 256, 0, stream>>>(cat, 512, sq, big, b0);
    k_select<<<dim3(sb * NN / 4), 256, 0, stream>>>(big, idx, b0, sb * NN);
  }
  k_yv<64, 64><<<dim3(256, 1), 256, 0, stream>>>(cat, 512, W2, g2, b2, y, v);
  k_agg<64, true><<<dim3(BB * NN / 4), 256, 0, stream>>>(y, v, idx, cat, 64, sq);

  // ---- layer 3: C=64 O=128, in=cat[:,64:128), out cols [128,256)
  for (int b0 = 0; b0 < BB; b0 += slabB) {
    int sb = BB - b0 < slabB ? BB - b0 : slabB;
    k_pd<64><<<dim3(32, 32, sb), 256, 0, stream>>>(cat + 64, 512, sq, big, b0);
    k_select<<<dim3(sb * NN / 4), 256, 0, stream>>>(big, idx, b0, sb * NN);
  }
  k_yv<64, 128><<<dim3(256, 2), 256, 0, stream>>>(cat + 64, 512, W3, g3, b3, y, v);
  k_agg<128, true><<<dim3(BB * NN / 2), 256, 0, stream>>>(y, v, idx, cat, 128, sq);

  // ---- layer 4: C=128 O=256, in=cat[:,128:256), out cols [256,512)
  for (int b0 = 0; b0 < BB; b0 += slabB) {
    int sb = BB - b0 < slabB ? BB - b0 : slabB;
    k_pd<128><<<dim3(32, 32, sb), 256, 0, stream>>>(cat + 128, 512, sq, big, b0);
    k_select<<<dim3(sb * NN / 4), 256, 0, stream>>>(big, idx, b0, sb * NN);
  }
  k_yv<128, 256><<<dim3(256, 4), 256, 0, stream>>>(cat + 128, 512, W4, g4, b4, y, v);
  k_agg<256, false><<<dim3(BB * NN), 256, 0, stream>>>(y, v, idx, cat, 256, nullptr);

  // ---- h5 + feat
  float* h5b = big;
  k_h5<<<dim3(256, 16), 256, 0, stream>>>(cat, W5, g5, b5, h5b);
  k_red1<<<dim3(4, 8, 8), 256, 0, stream>>>(h5b, pm, ps);
  k_red2<<<dim3(32), 256, 0, stream>>>(pm, ps, feat);

  // ---- FC head
  k_fc<<<dim3(1024), 256, 0, stream>>>(feat, Wl1, g6, b6, nullptr, fc1o, 2048, 512, 0);
  k_fc<<<dim3(512), 256, 0, stream>>>(fc1o, Wl2, g7, b7, bl2, fc2o, 512, 256, 1);
  k_fc<<<dim3(80), 256, 0, stream>>>(fc2o, Wl3, nullptr, nullptr, bl3, (float*)d_out, 256, 40, 2);
}

// Round 3
// 1081.480 us; speedup vs baseline: 1.8176x; 1.2594x over previous
//
#include <hip/hip_runtime.h>
#include <math.h>

#define BB 8
#define NN 2048
#define KNN 20
#define BN_INV 0.9999950000374997f

typedef __bf16 bf16x8 __attribute__((ext_vector_type(8)));
typedef __bf16 bf16x4 __attribute__((ext_vector_type(4)));
typedef float f32x4 __attribute__((ext_vector_type(4)));

// ---------------------------------------------------------------- unscramble
// x[b][n][c] = points_flat[b*6144 + c*2048 + n]; also sq = sum_c x^2
__global__ __launch_bounds__(256)
void k_unscramble(const float* __restrict__ pts, float* __restrict__ x0,
                  float* __restrict__ sq) {
  int t = blockIdx.x * 256 + threadIdx.x;
  if (t >= BB * NN) return;
  int b = t >> 11, n = t & (NN - 1);
  const float* p = pts + (size_t)b * 3 * NN;
  float a0 = p[n], a1 = p[NN + n], a2 = p[2 * NN + n];
  float* o = x0 + (size_t)t * 3;
  o[0] = a0; o[1] = a1; o[2] = a2;
  sq[t] = a0 * a0 + a1 * a1 + a2 * a2;
}

// ---------------------------------------------------------------- pd gemm
// score[i][j] = 2*dot(x_i,x_j) - sq[j]   (ranking-equivalent to reference pd)
// 64x64 tile, 256 threads, 4x4 per thread (A-rows STRIDED ti+16p: conflict-free)
template <int C>
__global__ __launch_bounds__(256)
void k_pd(const float* __restrict__ Xin, int RS, const float* __restrict__ sq,
          float* __restrict__ pd, int b0) {
  constexpr int CH = (C < 32) ? C : 32;
  constexpr int CHP = (CH == 3) ? 3 : 36;
  __shared__ __align__(16) float Xi[64 * CHP];
  __shared__ __align__(16) float Xj[64 * CHP];
  int b = b0 + blockIdx.z;
  int i0 = blockIdx.x * 64, j0 = blockIdx.y * 64;
  const float* Xb = Xin + (size_t)b * NN * RS;
  int ti = threadIdx.x & 15, tj = threadIdx.x >> 4;
  float acc[4][4] = {};
  for (int c0 = 0; c0 < C; c0 += CH) {
    if constexpr (CH == 32) {
      for (int t = threadIdx.x; t < 64 * 8; t += 256) {
        int r = t >> 3, c = (t & 7) * 4;
        *(float4*)&Xi[r * CHP + c] =
            *(const float4*)&Xb[(size_t)(i0 + r) * RS + c0 + c];
        *(float4*)&Xj[r * CHP + c] =
            *(const float4*)&Xb[(size_t)(j0 + r) * RS + c0 + c];
      }
    } else {
      for (int t = threadIdx.x; t < 64 * CH; t += 256) {
        int r = t / CH, c = t % CH;
        Xi[r * CHP + c] = Xb[(size_t)(i0 + r) * RS + c0 + c];
        Xj[r * CHP + c] = Xb[(size_t)(j0 + r) * RS + c0 + c];
      }
    }
    __syncthreads();
    if constexpr (CH % 4 == 0) {
      #pragma unroll
      for (int c = 0; c < CH; c += 4) {
        float4 ap[4], wq[4];
        #pragma unroll
        for (int p = 0; p < 4; p++)
          ap[p] = *(const float4*)&Xi[(ti + 16 * p) * CHP + c];
        #pragma unroll
        for (int q = 0; q < 4; q++)
          wq[q] = *(const float4*)&Xj[(tj * 4 + q) * CHP + c];
        #pragma unroll
        for (int p = 0; p < 4; p++)
          #pragma unroll
          for (int q = 0; q < 4; q++)
            acc[p][q] += ap[p].x * wq[q].x + ap[p].y * wq[q].y +
                         ap[p].z * wq[q].z + ap[p].w * wq[q].w;
      }
    } else {
      #pragma unroll
      for (int c = 0; c < CH; ++c) {
        float a[4], w[4];
        #pragma unroll
        for (int p = 0; p < 4; p++) a[p] = Xi[(ti + 16 * p) * CHP + c];
        #pragma unroll
        for (int q = 0; q < 4; q++) w[q] = Xj[(tj * 4 + q) * CHP + c];
        #pragma unroll
        for (int p = 0; p < 4; p++)
          #pragma unroll
          for (int q = 0; q < 4; q++) acc[p][q] += a[p] * w[q];
      }
    }
    __syncthreads();
  }
  const float* sqb = sq + (size_t)b * NN;
  float* pdb = pd + (size_t)blockIdx.z * NN * NN;
  #pragma unroll
  for (int p = 0; p < 4; p++) {
    int i = i0 + ti + 16 * p;
    int j = j0 + tj * 4;
    float4 o;
    o.x = 2.f * acc[p][0] - sqb[j + 0];
    o.y = 2.f * acc[p][1] - sqb[j + 1];
    o.z = 2.f * acc[p][2] - sqb[j + 2];
    o.w = 2.f * acc[p][3] - sqb[j + 3];
    *(float4*)&pdb[(size_t)i * NN + j] = o;
  }
}

// ---------------------------------------------------------------- knn select
__global__ __launch_bounds__(256)
void k_select(const float* __restrict__ pd, int* __restrict__ idx, int b0,
              int rows) {
  int wave = threadIdx.x >> 6;
  int lane = threadIdx.x & 63;
  int r = blockIdx.x * 4 + wave;  // slab-local row
  if (r >= rows) return;
  const float* row = pd + (size_t)r * NN;
  float rv[32];
  #pragma unroll
  for (int m = 0; m < 32; m++) rv[m] = row[m * 64 + lane];
  unsigned removed = 0u;
  int* out = idx + ((size_t)b0 * NN + r) * KNN;
  for (int k = 0; k < KNN; k++) {
    float lv = -INFINITY;
    int lm = 0;
    #pragma unroll
    for (int m = 0; m < 32; m++) {
      float vv = ((removed >> m) & 1u) ? -INFINITY : rv[m];
      if (vv > lv) { lv = vv; lm = m; }
    }
    float bv = lv;
    int bj = lm * 64 + lane;
    #pragma unroll
    for (int off = 32; off; off >>= 1) {
      float ov = __shfl_xor(bv, off, 64);
      int oj = __shfl_xor(bj, off, 64);
      if (ov > bv || (ov == bv && oj < bj)) { bv = ov; bj = oj; }
    }
    if (lane == 0) out[k] = bj;
    if (lane == (bj & 63)) removed |= (1u << (bj >> 6));
  }
}

// ---------------------------------------------------------------- y/v gemm
// y[n][o] = s_o * (Wa . x_n);  v[n][o] = s_o * ((Wb-Wa) . x_n) + b_o
template <int C, int O>
__global__ __launch_bounds__(256)
void k_yv(const float* __restrict__ Xin, int RS, const float* __restrict__ W,
          const float* __restrict__ g, const float* __restrict__ bbn,
          float* __restrict__ y, float* __restrict__ v) {
  constexpr int CH = (C < 32) ? C : 32;
  constexpr int CHP = (CH == 3) ? 3 : 36;
  __shared__ __align__(16) float Xs[64 * CHP];
  __shared__ __align__(16) float Wa[64 * CHP];
  __shared__ __align__(16) float Wd[64 * CHP];
  int r0 = blockIdx.x * 64, o0 = blockIdx.y * 64;
  int ti = threadIdx.x & 15, tj = threadIdx.x >> 4;
  float ay[4][4] = {}, av[4][4] = {};
  for (int c0 = 0; c0 < C; c0 += CH) {
    if constexpr (CH == 32) {
      for (int t = threadIdx.x; t < 64 * 8; t += 256) {
        int r = t >> 3, c = (t & 7) * 4;
        *(float4*)&Xs[r * CHP + c] =
            *(const float4*)&Xin[(size_t)(r0 + r) * RS + c0 + c];
        const float* wr = W + (size_t)(o0 + r) * (2 * C) + c0 + c;
        float4 wa4 = *(const float4*)wr;
        float4 wb4 = *(const float4*)(wr + C);
        *(float4*)&Wa[r * CHP + c] = wa4;
        float4 wd4;
        wd4.x = wb4.x - wa4.x; wd4.y = wb4.y - wa4.y;
        wd4.z = wb4.z - wa4.z; wd4.w = wb4.w - wa4.w;
        *(float4*)&Wd[r * CHP + c] = wd4;
      }
    } else {
      for (int t = threadIdx.x; t < 64 * CH; t += 256) {
        int r = t / CH, c = t % CH;
        Xs[r * CHP + c] = Xin[(size_t)(r0 + r) * RS + c0 + c];
        const float* wr = W + (size_t)(o0 + r) * (2 * C) + c0 + c;
        float wa_ = wr[0];
        Wa[r * CHP + c] = wa_;
        Wd[r * CHP + c] = wr[C] - wa_;
      }
    }
    __syncthreads();
    if constexpr (CH % 4 == 0) {
      #pragma unroll
      for (int c = 0; c < CH; c += 4) {
        float4 ap[4], qa[4], qd[4];
        #pragma unroll
        for (int p = 0; p < 4; p++)
          ap[p] = *(const float4*)&Xs[(ti + 16 * p) * CHP + c];
        #pragma unroll
        for (int q = 0; q < 4; q++) {
          qa[q] = *(const float4*)&Wa[(tj * 4 + q) * CHP + c];
          qd[q] = *(const float4*)&Wd[(tj * 4 + q) * CHP + c];
        }
        #pragma unroll
        for (int p = 0; p < 4; p++)
          #pragma unroll
          for (int q = 0; q < 4; q++) {
            ay[p][q] += ap[p].x * qa[q].x + ap[p].y * qa[q].y +
                        ap[p].z * qa[q].z + ap[p].w * qa[q].w;
            av[p][q] += ap[p].x * qd[q].x + ap[p].y * qd[q].y +
                        ap[p].z * qd[q].z + ap[p].w * qd[q].w;
          }
      }
    } else {
      #pragma unroll
      for (int c = 0; c < CH; ++c) {
        float a[4];
        #pragma unroll
        for (int p = 0; p < 4; p++) a[p] = Xs[(ti + 16 * p) * CHP + c];
        #pragma unroll
        for (int q = 0; q < 4; q++) {
          float wa_ = Wa[(tj * 4 + q) * CHP + c];
          float wd_ = Wd[(tj * 4 + q) * CHP + c];
          #pragma unroll
          for (int p = 0; p < 4; p++) {
            ay[p][q] += a[p] * wa_;
            av[p][q] += a[p] * wd_;
          }
        }
      }
    }
    __syncthreads();
  }
  #pragma unroll
  for (int p = 0; p < 4; p++) {
    int row = r0 + ti + 16 * p;
    float oy[4], ov[4];
    #pragma unroll
    for (int q = 0; q < 4; q++) {
      int o = o0 + tj * 4 + q;
      float s = BN_INV * g[o];
      oy[q] = s * ay[p][q];
      ov[q] = s * av[p][q] + bbn[o];
    }
    *(float4*)&y[(size_t)row * O + o0 + tj * 4] = *(float4*)oy;
    *(float4*)&v[(size_t)row * O + o0 + tj * 4] = *(float4*)ov;
  }
}

// ---------------------------------------------------------------- aggregate
template <int O, bool DO_SQ>
__global__ __launch_bounds__(256)
void k_agg(const float* __restrict__ y, const float* __restrict__ v,
           const int* __restrict__ idx, float* __restrict__ cat_out, int coloff,
           float* __restrict__ sqo) {
  constexpr int RPB = 256 / O;
  int rl = threadIdx.x / O;
  int o = threadIdx.x % O;
  int row = blockIdx.x * RPB + rl;  // b*N+n
  int b = row >> 11;
  const int* ix = idx + (size_t)row * KNN;
  float vv = v[(size_t)row * O + o];
  const float* yb = y + (size_t)b * NN * O;
  float m = -INFINITY;
  #pragma unroll
  for (int k = 0; k < KNN; k++) {
    int j = ix[k];
    m = fmaxf(m, yb[(size_t)j * O + o] + vv);
  }
  float out = m >= 0.f ? m : 0.2f * m;
  cat_out[(size_t)row * 512 + coloff + o] = out;
  if constexpr (DO_SQ) {
    constexpr int WPR = O / 64;
    float p2 = out * out;
    #pragma unroll
    for (int off = 32; off; off >>= 1) p2 += __shfl_xor(p2, off, 64);
    __shared__ float part[4];
    int wv = threadIdx.x >> 6;
    if ((threadIdx.x & 63) == 0) part[wv] = p2;
    __syncthreads();
    if ((threadIdx.x % O) == 0) {
      int w0 = threadIdx.x >> 6;
      float s = 0.f;
      #pragma unroll
      for (int w = 0; w < WPR; ++w) s += part[w0 + w];
      sqo[row] = s;
    }
  }
}

// ---------------------------------------------------------------- h5 gemm (bf16 MFMA)
// [16384,512] x [512,1024]^T, epilogue lrelu(bn). 128x128 tile, 4 waves 2x2,
// 4x4 16x16x32 fragments per wave, BK=64. fp32->bf16 fused into staging.
// LDS XOR-swizzle (T2): 16B chunk c -> c ^ (row&7); write/read both sides.
__global__ __launch_bounds__(256)
void k_h5m(const float* __restrict__ A, const float* __restrict__ W5,
           const float* __restrict__ g, const float* __restrict__ bbn,
           float* __restrict__ out) {
  __shared__ __align__(16) __bf16 Al[128 * 64];
  __shared__ __align__(16) __bf16 Bl[128 * 64];
  int m0 = blockIdx.x * 128, o0 = blockIdx.y * 128;
  int w = threadIdx.x >> 6, lane = threadIdx.x & 63;
  int wm = w >> 1, wn = w & 1;
  f32x4 acc[4][4];
  #pragma unroll
  for (int f = 0; f < 4; f++)
    #pragma unroll
    for (int j = 0; j < 4; j++) acc[f][j] = (f32x4){0.f, 0.f, 0.f, 0.f};

  int wr0 = w * 32;
  int c8 = lane & 15;
  for (int k0 = 0; k0 < 512; k0 += 64) {
    #pragma unroll
    for (int i = 0; i < 8; i++) {
      int row = wr0 + i * 4 + (lane >> 4);
      float4 a4 = *(const float4*)&A[(size_t)(m0 + row) * 512 + k0 + c8 * 4];
      float4 b4 = *(const float4*)&W5[(size_t)(o0 + row) * 512 + k0 + c8 * 4];
      int el = (c8 * 4) ^ ((row & 7) << 3);
      bf16x4 ah, bh;
      ah.x = (__bf16)a4.x; ah.y = (__bf16)a4.y; ah.z = (__bf16)a4.z; ah.w = (__bf16)a4.w;
      bh.x = (__bf16)b4.x; bh.y = (__bf16)b4.y; bh.z = (__bf16)b4.z; bh.w = (__bf16)b4.w;
      *(bf16x4*)&Al[row * 64 + el] = ah;
      *(bf16x4*)&Bl[row * 64 + el] = bh;
    }
    __syncthreads();
    #pragma unroll
    for (int kk = 0; kk < 2; kk++) {
      bf16x8 af[4], bfr[4];
      int cb = (lane >> 4) + kk * 4;
      #pragma unroll
      for (int f = 0; f < 4; f++) {
        int ra = wm * 64 + f * 16 + (lane & 15);
        af[f] = *(const bf16x8*)&Al[ra * 64 + ((cb ^ (ra & 7)) * 8)];
        int rb = wn * 64 + f * 16 + (lane & 15);
        bfr[f] = *(const bf16x8*)&Bl[rb * 64 + ((cb ^ (rb & 7)) * 8)];
      }
      #pragma unroll
      for (int f = 0; f < 4; f++)
        #pragma unroll
        for (int j = 0; j < 4; j++)
          acc[f][j] = __builtin_amdgcn_mfma_f32_16x16x32_bf16(af[f], bfr[j],
                                                              acc[f][j], 0, 0, 0);
    }
    __syncthreads();
  }
  #pragma unroll
  for (int f = 0; f < 4; f++) {
    int mrow = m0 + wm * 64 + f * 16 + (lane >> 4) * 4;
    #pragma unroll
    for (int j = 0; j < 4; j++) {
      int o = o0 + wn * 64 + j * 16 + (lane & 15);
      float s = BN_INV * g[o], bb = bbn[o];
      #pragma unroll
      for (int r = 0; r < 4; r++) {
        float z = s * acc[f][j][r] + bb;
        z = z >= 0.f ? z : 0.2f * z;
        out[(size_t)(mrow + r) * 1024 + o] = z;
      }
    }
  }
}

// ---------------------------------------------------------------- reductions
__global__ __launch_bounds__(256)
void k_red1(const float* __restrict__ h5, float* __restrict__ pm,
            float* __restrict__ ps) {
  int oc = blockIdx.x, ns = blockIdx.y, b = blockIdx.z;
  int o = oc * 256 + threadIdx.x;
  const float* hp = h5 + ((size_t)b * NN + ns * 256) * 1024 + o;
  float m = -INFINITY, s = 0.f;
  for (int t = 0; t < 256; ++t) {
    float x = hp[(size_t)t * 1024];
    m = fmaxf(m, x);
    s += x;
  }
  pm[(size_t)(b * 8 + ns) * 1024 + o] = m;
  ps[(size_t)(b * 8 + ns) * 1024 + o] = s;
}

__global__ __launch_bounds__(256)
void k_red2(const float* __restrict__ pm, const float* __restrict__ ps,
            float* __restrict__ feat) {
  int gg = blockIdx.x * 256 + threadIdx.x;
  if (gg >= BB * 1024) return;
  int b = gg >> 10, o = gg & 1023;
  float m = -INFINITY, s = 0.f;
  for (int ns = 0; ns < 8; ++ns) {
    m = fmaxf(m, pm[(size_t)(b * 8 + ns) * 1024 + o]);
    s += ps[(size_t)(b * 8 + ns) * 1024 + o];
  }
  feat[(size_t)b * 2048 + o] = m;
  feat[(size_t)b * 2048 + 1024 + o] = s * (1.f / 2048.f);
}

// ---------------------------------------------------------------- FC layers
__global__ __launch_bounds__(256)
void k_fc(const float* __restrict__ in, const float* __restrict__ W,
          const float* __restrict__ g, const float* __restrict__ bbn,
          const float* __restrict__ eb, float* __restrict__ out, int IN, int O,
          int mode) {
  int gid = (blockIdx.x * 256 + threadIdx.x) >> 6;
  int lane = threadIdx.x & 63;
  int b = gid / O, o = gid % O;
  if (b >= BB) return;
  const float* ip = in + (size_t)b * IN;
  const float* wp = W + (size_t)o * IN;
  float acc = 0.f;
  for (int i = lane; i < IN; i += 64) acc += ip[i] * wp[i];
  #pragma unroll
  for (int off = 32; off; off >>= 1) acc += __shfl_xor(acc, off, 64);
  if (lane == 0) {
    float z;
    if (mode == 0) {
      z = BN_INV * g[o] * acc + bbn[o];
      z = z >= 0.f ? z : 0.2f * z;
    } else if (mode == 1) {
      z = BN_INV * g[o] * (acc + eb[o]) + bbn[o];
      z = z >= 0.f ? z : 0.2f * z;
    } else {
      z = acc + eb[o];
    }
    out[(size_t)b * O + o] = z;
  }
}

// ---------------------------------------------------------------- host
extern "C" void kernel_launch(void* const* d_in, const int* in_sizes, int n_in,
                              void* d_out, int out_size, void* d_ws,
                              size_t ws_size, hipStream_t stream) {
  (void)in_sizes; (void)n_in; (void)out_size;
  const float* pts = (const float*)d_in[0];
  const float* W1 = (const float*)d_in[1];
  const float* g1 = (const float*)d_in[2];
  const float* b1 = (const float*)d_in[3];
  const float* W2 = (const float*)d_in[4];
  const float* g2 = (const float*)d_in[5];
  const float* b2 = (const float*)d_in[6];
  const float* W3 = (const float*)d_in[7];
  const float* g3 = (const float*)d_in[8];
  const float* b3 = (const float*)d_in[9];
  const float* W4 = (const float*)d_in[10];
  const float* g4 = (const float*)d_in[11];
  const float* b4 = (const float*)d_in[12];
  const float* W5 = (const float*)d_in[13];
  const float* g5 = (const float*)d_in[14];
  const float* b5 = (const float*)d_in[15];
  const float* Wl1 = (const float*)d_in[16];
  const float* g6 = (const float*)d_in[17];
  const float* b6 = (const float*)d_in[18];
  const float* Wl2 = (const float*)d_in[19];
  const float* bl2 = (const float*)d_in[20];
  const float* g7 = (const float*)d_in[21];
  const float* b7 = (const float*)d_in[22];
  const float* Wl3 = (const float*)d_in[23];
  const float* bl3 = (const float*)d_in[24];

  char* ws = (char*)d_ws;
  float* x0 = (float*)(ws + 0);                  // 196608
  float* cat = (float*)(ws + 196608);            // 33554432
  float* sq = (float*)(ws + 33751040);           // 65536
  int* idx = (int*)(ws + 33816576);              // 1310720
  float* y = (float*)(ws + 35127296);            // 16777216
  float* v = (float*)(ws + 51904512);            // 16777216
  float* pm = (float*)(ws + 68681728);           // 262144
  float* ps = (float*)(ws + 68943872);           // 262144
  float* feat = (float*)(ws + 69206016);         // 65536
  float* fc1o = (float*)(ws + 69271552);         // 16384
  float* fc2o = (float*)(ws + 69287936);         // 8192
  float* big = (float*)(ws + 69296128);          // pd slab / h5 (shared)

  size_t avail = ws_size > (size_t)69296128 ? ws_size - (size_t)69296128 : 0;
  int slabB = (int)(avail / ((size_t)NN * NN * 4));
  if (slabB > BB) slabB = BB;
  if (slabB < 1) slabB = 1;

  k_unscramble<<<dim3(64), 256, 0, stream>>>(pts, x0, sq);

  // ---- layer 1: C=3 O=64, in=x0(RS 3), out cols [0,64)
  for (int b0 = 0; b0 < BB; b0 += slabB) {
    int sb = BB - b0 < slabB ? BB - b0 : slabB;
    k_pd<3><<<dim3(32, 32, sb), 256, 0, stream>>>(x0, 3, sq, big, b0);
    k_select<<<dim3(sb * NN / 4), 256, 0, stream>>>(big, idx, b0, sb * NN);
  }
  k_yv<3, 64><<<dim3(256, 1), 256, 0, stream>>>(x0, 3, W1, g1, b1, y, v);
  k_agg<64, true><<<dim3(BB * NN / 4), 256, 0, stream>>>(y, v, idx, cat, 0, sq);

  // ---- layer 2: C=64 O=64, in=cat[:,0:64), out cols [64,128)
  for (int b0 = 0; b0 < BB; b0 += slabB) {
    int sb = BB - b0 < slabB ? BB - b0 : slabB;
    k_pd<64><<<dim3(32, 32, sb), 256, 0, stream>>>(cat, 512, sq, big, b0);
    k_select<<<dim3(sb * NN / 4), 256, 0, stream>>>(big, idx, b0, sb * NN);
  }
  k_yv<64, 64><<<dim3(256, 1), 256, 0, stream>>>(cat, 512, W2, g2, b2, y, v);
  k_agg<64, true><<<dim3(BB * NN / 4), 256, 0, stream>>>(y, v, idx, cat, 64, sq);

  // ---- layer 3: C=64 O=128, in=cat[:,64:128), out cols [128,256)
  for (int b0 = 0; b0 < BB; b0 += slabB) {
    int sb = BB - b0 < slabB ? BB - b0 : slabB;
    k_pd<64><<<dim3(32, 32, sb), 256, 0, stream>>>(cat + 64, 512, sq, big, b0);
    k_select<<<dim3(sb * NN / 4), 256, 0, stream>>>(big, idx, b0, sb * NN);
  }
  k_yv<64, 128><<<dim3(256, 2), 256, 0, stream>>>(cat + 64, 512, W3, g3, b3, y, v);
  k_agg<128, true><<<dim3(BB * NN / 2), 256, 0, stream>>>(y, v, idx, cat, 128, sq);

  // ---- layer 4: C=128 O=256, in=cat[:,128:256), out cols [256,512)
  for (int b0 = 0; b0 < BB; b0 += slabB) {
    int sb = BB - b0 < slabB ? BB - b0 : slabB;
    k_pd<128><<<dim3(32, 32, sb), 256, 0, stream>>>(cat + 128, 512, sq, big, b0);
    k_select<<<dim3(sb * NN / 4), 256, 0, stream>>>(big, idx, b0, sb * NN);
  }
  k_yv<128, 256><<<dim3(256, 4), 256, 0, stream>>>(cat + 128, 512, W4, g4, b4, y, v);
  k_agg<256, false><<<dim3(BB * NN), 256, 0, stream>>>(y, v, idx, cat, 256, nullptr);

  // ---- h5 (bf16 MFMA) + feat
  float* h5b = big;
  k_h5m<<<dim3(128, 8), 256, 0, stream>>>(cat, W5, g5, b5, h5b);
  k_red1<<<dim3(4, 8, 8), 256, 0, stream>>>(h5b, pm, ps);
  k_red2<<<dim3(32), 256, 0, stream>>>(pm, ps, feat);

  // ---- FC head
  k_fc<<<dim3(1024), 256, 0, stream>>>(feat, Wl1, g6, b6, nullptr, fc1o, 2048, 512, 0);
  k_fc<<<dim3(512), 256, 0, stream>>>(fc1o, Wl2, g7, b7, bl2, fc2o, 512, 256, 1);
  k_fc<<<dim3(80), 256, 0, stream>>>(fc2o, Wl3, nullptr, nullptr, bl3, (float*)d_out, 256, 40, 2);
}